// Round 15
// baseline (136.174 us; speedup 1.0000x reference)
//
#include <hip/hip_runtime.h>
#include <stdint.h>

typedef unsigned short u16;
typedef __attribute__((ext_vector_type(4))) float f32x4;
typedef __attribute__((ext_vector_type(16))) float f32x16;
typedef __attribute__((ext_vector_type(8))) __bf16 bf16x8;
typedef __attribute__((ext_vector_type(8))) unsigned short u16x8;
typedef __attribute__((ext_vector_type(4))) unsigned short u16x4;

#define DIM_    1024
#define NHEADS_ 16
#define HD_     64
#define BB_     2
#define NN_     2048
#define MM_     2048

// 0.125 * log2(e): folded into Q projection so softmax runs in base-2.
#define QSCALE 0.180336884f

__device__ inline u16 f32_to_bf16u(float f) {
  union { float f; uint32_t u; } x; x.f = f;
  uint32_t r = x.u + 0x7FFFu + ((x.u >> 16) & 1u);
  return (u16)(r >> 16);
}
__device__ inline float bf16u_to_f32(u16 h) {
  union { uint32_t u; float f; } x; x.u = ((uint32_t)h) << 16;
  return x.f;
}

__device__ inline void gload_lds16(const u16* g, u16* l) {
  u16* gnc = const_cast<u16*>(g);
  __builtin_amdgcn_global_load_lds(
      (__attribute__((address_space(1))) void*)gnc,
      (__attribute__((address_space(3))) void*)l, 16, 0, 0);
}

__device__ inline uint32_t cvt_pk_bf16(float lo, float hi) {
  uint32_t r;
  asm("v_cvt_pk_bf16_f32 %0, %1, %2" : "=v"(r) : "v"(lo), "v"(hi));
  return r;
}
__device__ inline void permlane32_swap(uint32_t& a, uint32_t& b) {
  asm("v_permlane32_swap_b32 %0, %1" : "+v"(a), "+v"(b));
}

// ---------------- fused cast fp32 -> bf16 (all 6 tensors, one launch) ------
__global__ void cast_all(const float* s0, u16* d0, const float* s1, u16* d1,
                         const float* s2, u16* d2, const float* s3, u16* d3,
                         const float* s4, u16* d4, const float* s5, u16* d5) {
  const float* s; u16* d; int n4;
  switch (blockIdx.y) {
    case 0: s = s0; d = d0; n4 = (BB_ * NN_ * DIM_) / 4; break;
    case 1: s = s1; d = d1; n4 = (BB_ * MM_ * DIM_) / 4; break;
    case 2: s = s2; d = d2; n4 = (DIM_ * DIM_) / 4; break;
    case 3: s = s3; d = d3; n4 = (DIM_ * DIM_) / 4; break;
    case 4: s = s4; d = d4; n4 = (DIM_ * DIM_) / 4; break;
    default: s = s5; d = d5; n4 = (DIM_ * DIM_) / 4; break;
  }
  int stride = gridDim.x * blockDim.x;
  for (int i = blockIdx.x * blockDim.x + threadIdx.x; i < n4; i += stride) {
    float4 f = reinterpret_cast<const float4*>(s)[i];
    u16x4 u;
    u.x = f32_to_bf16u(f.x);
    u.y = f32_to_bf16u(f.y);
    u.z = f32_to_bf16u(f.z);
    u.w = f32_to_bf16u(f.w);
    reinterpret_cast<u16x4*>(d)[i] = u;
  }
}

// ---------------- GEMM core (BK=64) : used by gemm_o -----------------------
#define BM 128
#define BN 128
#define BK 64

template <bool BF16OUT>
__device__ __forceinline__
void gemm_body(const u16* __restrict__ A, const u16* __restrict__ Bm,
               const float* __restrict__ bias, void* __restrict__ Cout,
               int M, int N, int K, float scale,
               u16* As /*2*BM*BK*/, u16* Bs /*2*BN*BK*/) {
  const int tid  = threadIdx.x;
  const int lane = tid & 63;
  const int wid  = tid >> 6;
  const int wr = wid >> 2, wc = wid & 3;          // 2 x 4 wave grid
  const int fr = lane & 15, fq = lane >> 4;
  const int bm = blockIdx.x, bn = blockIdx.y;
  const int lrow = lane >> 3;                     // 0..7
  const int scol = (((lane & 7) ^ lrow) * 8);     // pre-swizzled source col

  f32x4 acc[4][2];
  #pragma unroll
  for (int m = 0; m < 4; ++m)
    #pragma unroll
    for (int n = 0; n < 2; ++n)
      acc[m][n] = f32x4{0.f, 0.f, 0.f, 0.f};

  const int NT = K / BK;

  auto stage = [&](int buf, int t) {
    int k0 = t * BK;
    #pragma unroll
    for (int c = 0; c < 2; ++c) {
      int ch  = wid * 2 + c;           // 0..15
      int row = ch * 8 + lrow;         // 0..127
      gload_lds16(A  + (size_t)(bm * BM + row) * K + k0 + scol, &As[buf * BM * BK + ch * 512]);
      gload_lds16(Bm + (size_t)(bn * BN + row) * K + k0 + scol, &Bs[buf * BN * BK + ch * 512]);
    }
  };

  stage(0, 0);
  __syncthreads();
  int cur = 0;
  for (int t = 0; t < NT; ++t) {
    if (t + 1 < NT) stage(cur ^ 1, t + 1);
    #pragma unroll
    for (int ks = 0; ks < 2; ++ks) {
      bf16x8 af[4], bfr[2];
      #pragma unroll
      for (int m = 0; m < 4; ++m)
        af[m] = *reinterpret_cast<const bf16x8*>(
            &As[cur * BM * BK + (wr * 64 + m * 16 + fr) * BK + (((ks * 4 + fq) ^ (fr & 7)) * 8)]);
      #pragma unroll
      for (int n = 0; n < 2; ++n)
        bfr[n] = *reinterpret_cast<const bf16x8*>(
            &Bs[cur * BN * BK + (wc * 32 + n * 16 + fr) * BK + (((ks * 4 + fq) ^ (fr & 7)) * 8)]);
      __builtin_amdgcn_s_setprio(1);
      #pragma unroll
      for (int m = 0; m < 4; ++m)
        #pragma unroll
        for (int n = 0; n < 2; ++n)
          acc[m][n] = __builtin_amdgcn_mfma_f32_16x16x32_bf16(af[m], bfr[n], acc[m][n], 0, 0, 0);
      __builtin_amdgcn_s_setprio(0);
    }
    __syncthreads();
    cur ^= 1;
  }

  #pragma unroll
  for (int n = 0; n < 2; ++n) {
    int col = bn * BN + wc * 32 + n * 16 + fr;
    float bv = bias[col];
    #pragma unroll
    for (int m = 0; m < 4; ++m) {
      #pragma unroll
      for (int i = 0; i < 4; ++i) {
        int row = bm * BM + wr * 64 + m * 16 + fq * 4 + i;
        float v = (acc[m][n][i] + bv) * scale;
        if (BF16OUT)
          ((u16*)Cout)[(size_t)row * N + col] = f32_to_bf16u(v);
        else
          ((float*)Cout)[(size_t)row * N + col] = v;
      }
    }
  }
}

// ---------- QKV GEMM, BK=32 (R14 proven): 3 blocks/CU resident -------------
#define BK2 32

__global__ __launch_bounds__(512)
void gemm_qkv(const u16* __restrict__ x1b, const u16* __restrict__ x2b,
              const u16* __restrict__ Wqb, const float* __restrict__ bq, u16* qb,
              const u16* __restrict__ Wkb, const float* __restrict__ bk, u16* kb,
              const u16* __restrict__ Wvb, const float* __restrict__ bv, u16* vb) {
  __shared__ __align__(16) u16 As[2 * BM * BK2];   // 16 KB
  __shared__ __align__(16) u16 Bs[2 * BN * BK2];   // 16 KB
  const u16* A; const u16* W; const float* bias; u16* C; float scale;
  switch (blockIdx.z) {
    case 0:  A = x1b; W = Wqb; bias = bq; C = qb; scale = QSCALE; break;
    case 1:  A = x2b; W = Wkb; bias = bk; C = kb; scale = 1.0f;   break;
    default: A = x2b; W = Wvb; bias = bv; C = vb; scale = 1.0f;   break;
  }
  const int K = DIM_;
  const int tid  = threadIdx.x;
  const int lane = tid & 63;
  const int wid  = tid >> 6;
  const int wr = wid >> 2, wc = wid & 3;
  const int fr = lane & 15, fq = lane >> 4;
  const int bm = blockIdx.x, bn = blockIdx.y;

  const int srow = tid >> 2;                        // 0..127
  const int sch  = tid & 3;                         // chunk 0..3
  const int scol = ((sch ^ ((srow >> 1) & 3)) * 8); // pre-swizzled src col (u16)
  const int rsw  = (fr >> 1) & 3;                   // read-side swizzle key

  f32x4 acc[4][2];
  #pragma unroll
  for (int m = 0; m < 4; ++m)
    #pragma unroll
    for (int n = 0; n < 2; ++n)
      acc[m][n] = f32x4{0.f, 0.f, 0.f, 0.f};

  const int NT = K / BK2;   // 32

  auto stage = [&](int buf, int t) {
    int k0 = t * BK2;
    gload_lds16(x1b == A || x2b == A ? A + (size_t)(bm * BM + srow) * K + k0 + scol
                                     : A, &As[buf * BM * BK2 + tid * 8]);
    gload_lds16(W + (size_t)(bn * BN + srow) * K + k0 + scol, &Bs[buf * BN * BK2 + tid * 8]);
  };
  // (the ternary above always takes the first branch; kept simple)

  stage(0, 0);
  __syncthreads();
  int cur = 0;
  for (int t = 0; t < NT; ++t) {
    if (t + 1 < NT) stage(cur ^ 1, t + 1);
    bf16x8 af[4], bfr[2];
    #pragma unroll
    for (int m = 0; m < 4; ++m)
      af[m] = *reinterpret_cast<const bf16x8*>(
          &As[cur * BM * BK2 + (wr * 64 + m * 16 + fr) * BK2 + ((fq ^ rsw) * 8)]);
    #pragma unroll
    for (int n = 0; n < 2; ++n)
      bfr[n] = *reinterpret_cast<const bf16x8*>(
          &Bs[cur * BN * BK2 + (wc * 32 + n * 16 + fr) * BK2 + ((fq ^ rsw) * 8)]);
    __builtin_amdgcn_s_setprio(1);
    #pragma unroll
    for (int m = 0; m < 4; ++m)
      #pragma unroll
      for (int n = 0; n < 2; ++n)
        acc[m][n] = __builtin_amdgcn_mfma_f32_16x16x32_bf16(af[m], bfr[n], acc[m][n], 0, 0, 0);
    __builtin_amdgcn_s_setprio(0);
    __syncthreads();
    cur ^= 1;
  }

  #pragma unroll
  for (int n = 0; n < 2; ++n) {
    int col = bn * BN + wc * 32 + n * 16 + fr;
    float bv = bias[col];
    #pragma unroll
    for (int m = 0; m < 4; ++m) {
      #pragma unroll
      for (int i = 0; i < 4; ++i) {
        int row = bm * BM + wr * 64 + m * 16 + fq * 4 + i;
        float v = (acc[m][n][i] + bv) * scale;
        C[(size_t)row * DIM_ + col] = f32_to_bf16u(v);
      }
    }
  }
}

// O projection (fp32 out), bf16 A (reduced attn output) + bf16 W, BK=64 core.
__global__ __launch_bounds__(512)
void gemm_o(const u16* __restrict__ A, const u16* __restrict__ W,
            const float* __restrict__ bias, float* __restrict__ C) {
  __shared__ __align__(16) u16 As[2 * BM * BK];
  __shared__ __align__(16) u16 Bs[2 * BN * BK];
  gemm_body<false>(A, W, bias, C, BB_ * NN_, DIM_, DIM_, 1.0f, As, Bs);
}

// ---------------- flash attention, kv-split-2 ------------------------------
// 1024 blocks (XCD-swizzled; the 16 q-blocks of a (b,h,half) share an XCD),
// 512 threads = 8 waves = 4 q-groups x 2 kv-halves-within-block. Each block
// covers HALF the kv range (16 tiles) -> 4 blocks/CU, 32 waves/CU.
// 2-buffer LDS ring (~34 KB incl. epilogue), 1 barrier/tile.
// Writes UNNORMALIZED partial O (bf16) + partial l (f32); reduce_o combines.
#define QB 128
#define KVB 64

__global__ __launch_bounds__(512)
void attn_fwd(const u16* __restrict__ qg, const u16* __restrict__ kg,
              const u16* __restrict__ vg,
              u16* __restrict__ O0, u16* __restrict__ O1,
              float* __restrict__ L0, float* __restrict__ L1) {
  // ring: K bufs @0,@4096; VT bufs @8192,@12288 (u16). epilogue overlays:
  // Od f32[128][65] (8320 f32) + Ls f32[128] -> 8448 f32 = 16896 u16 total.
  __shared__ __align__(16) u16 KVs[16896];
  const int tid = threadIdx.x, lane = tid & 63, wid = tid >> 6;
  const int hi = lane >> 5;
  const int l31 = lane & 31;
  const int wq = wid >> 1, wk = wid & 1;

  // XCD swizzle (bijective: 1024 = 8 xcd * 16 r * 8 gg)
  int lin = blockIdx.x + gridDim.x * (blockIdx.y + gridDim.y * blockIdx.z);
  int xcd = lin & 7, slot = lin >> 3;
  int r = slot & 15, gg2 = slot >> 4;      // gg2 0..7
  int g = xcd + 8 * gg2;                   // group 0..63 = (half,b,h)
  int h = g & 15, bhf = g >> 4;            // bhf 0..3
  int b = bhf & 1, half = bhf >> 1;

  u16*  od = half ? O1 : O0;
  float* ld = half ? L1 : L0;
  const int kvbase = half * (MM_ / 2);

  const size_t base_q  = (size_t)b * NN_ * DIM_ + (size_t)h * HD_;
  const size_t base_kv = (size_t)b * MM_ * DIM_ + (size_t)h * HD_;
  const int lrow = lane >> 3;
  const int scol = (((lane & 7) ^ lrow) * 8);   // pre-swizzled K source col

  bf16x8 qf[4];
  const int qrow = r * QB + wq * 32 + l31;
  #pragma unroll
  for (int step = 0; step < 4; ++step)
    qf[step] = *reinterpret_cast<const bf16x8*>(
        qg + base_q + (size_t)qrow * DIM_ + step * 16 + hi * 8);

  bf16x8 onesf;
  #pragma unroll
  for (int j = 0; j < 8; ++j) onesf[j] = (__bf16)1.0f;

  f32x16 oacc[2];
  #pragma unroll
  for (int dgrp = 0; dgrp < 2; ++dgrp)
    #pragma unroll
    for (int rg = 0; rg < 16; ++rg) oacc[dgrp][rg] = 0.f;
  f32x16 lacc;
  #pragma unroll
  for (int rg = 0; rg < 16; ++rg) lacc[rg] = 0.f;

  const int NT = (MM_ / 2) / KVB;   // 16

  auto stageK = [&](int buf, int t) {
    int kv0 = kvbase + t * KVB;
    int row = wid * 8 + lrow;
    gload_lds16(kg + base_kv + (size_t)(kv0 + row) * DIM_ + scol,
                &KVs[buf * 4096 + wid * 512]);
  };
  auto loadV = [&](int t, u16x8& vpre) {
    int kv0 = kvbase + t * KVB;
    vpre = *reinterpret_cast<const u16x8*>(vg + base_kv + (size_t)(kv0 + lane) * DIM_ + wid * 8);
  };
  auto writeVT = [&](int buf, const u16x8& vpre) {
    #pragma unroll
    for (int j = 0; j < 8; ++j)
      KVs[(2 + buf) * 4096 + (wid * 8 + j) * KVB + (((lane >> 3) ^ j) * 8) + (lane & 7)] = vpre[j];
  };

  union PB { uint32_t w[4]; bf16x8 v; };

  auto compute = [&](int buf) {
    const u16* Kb = &KVs[buf * 4096];
    const u16* Vb = &KVs[(2 + buf) * 4096];
    f32x16 s;
    #pragma unroll
    for (int rg = 0; rg < 16; ++rg) s[rg] = 0.f;
    __builtin_amdgcn_s_setprio(1);
    #pragma unroll
    for (int step = 0; step < 4; ++step) {
      bf16x8 kf = *reinterpret_cast<const bf16x8*>(
          (const char*)Kb + (wk * 32 + l31) * 128 + (((step * 2 + hi) ^ (lane & 7)) * 16));
      s = __builtin_amdgcn_mfma_f32_32x32x16_bf16(kf, qf[step], s, 0, 0, 0);
    }
    __builtin_amdgcn_s_setprio(0);

    float p[16];
    #pragma unroll
    for (int rg = 0; rg < 16; ++rg) p[rg] = __builtin_amdgcn_exp2f(s[rg]);

    PB pb[2];
    #pragma unroll
    for (int u = 0; u < 2; ++u) {
      uint32_t x0 = cvt_pk_bf16(p[u * 8 + 0], p[u * 8 + 1]);
      uint32_t y0 = cvt_pk_bf16(p[u * 8 + 4], p[u * 8 + 5]);
      permlane32_swap(x0, y0);
      uint32_t x1 = cvt_pk_bf16(p[u * 8 + 2], p[u * 8 + 3]);
      uint32_t y1 = cvt_pk_bf16(p[u * 8 + 6], p[u * 8 + 7]);
      permlane32_swap(x1, y1);
      pb[u].w[0] = x0; pb[u].w[1] = x1; pb[u].w[2] = y0; pb[u].w[3] = y1;
    }

    __builtin_amdgcn_s_setprio(1);
    #pragma unroll
    for (int u = 0; u < 2; ++u)
      lacc = __builtin_amdgcn_mfma_f32_32x32x16_bf16(onesf, pb[u].v, lacc, 0, 0, 0);
    #pragma unroll
    for (int dgrp = 0; dgrp < 2; ++dgrp)
      #pragma unroll
      for (int u = 0; u < 2; ++u) {
        bf16x8 vf = *reinterpret_cast<const bf16x8*>(
            (const char*)Vb + (dgrp * 32 + l31) * 128 +
            (((wk * 4 + u * 2 + hi) ^ (lane & 7)) * 16));
        oacc[dgrp] = __builtin_amdgcn_mfma_f32_32x32x16_bf16(vf, pb[u].v, oacc[dgrp], 0, 0, 0);
      }
    __builtin_amdgcn_s_setprio(0);
  };

  // prologue: stage tile 0 into buf 0
  {
    u16x8 v0;
    loadV(0, v0);
    stageK(0, 0);
    writeVT(0, v0);
    __syncthreads();
  }

  // main loop: 2-buffer ring, stage t+1 while computing t, 1 barrier/tile.
  int cur = 0;
  for (int t = 0; t < NT; ++t) {
    u16x8 vpre;
    bool pre = (t + 1 < NT);
    if (pre) {
      loadV(t + 1, vpre);
      stageK(cur ^ 1, t + 1);
    }
    compute(cur);
    if (pre) writeVT(cur ^ 1, vpre);
    __syncthreads();
    cur ^= 1;
  }

  // ---- epilogue: cross-wk partial-O reduction, UNNORMALIZED, fenced -------
  float* Od = (float*)&KVs[0];             // [128][65] f32
  float* Ls = (float*)&KVs[0] + 128 * 65;  // [128] f32
  u16*  Of  = (u16*)&KVs[0];               // [128][68] u16 overlay

  // phase 1: wk==1 publishes partial O and l
  if (wk == 1) {
    #pragma unroll
    for (int dgrp = 0; dgrp < 2; ++dgrp)
      #pragma unroll
      for (int rg = 0; rg < 16; ++rg) {
        int d = dgrp * 32 + (rg & 3) + 8 * (rg >> 2) + 4 * hi;
        Od[(wq * 32 + l31) * 65 + d] = oacc[dgrp][rg];
      }
    if (hi == 0) Ls[wq * 32 + l31] = lacc[0];
  }
  __syncthreads();
  // phase 2: wk==0 sums (no normalization); writes partial l to global
  if (wk == 0) {
    #pragma unroll
    for (int dgrp = 0; dgrp < 2; ++dgrp)
      #pragma unroll
      for (int rg = 0; rg < 16; ++rg) {
        int d = dgrp * 32 + (rg & 3) + 8 * (rg >> 2) + 4 * hi;
        oacc[dgrp][rg] += Od[(wq * 32 + l31) * 65 + d];
      }
    if (hi == 0) {
      int qglob = r * QB + wq * 32 + l31;
      ld[((size_t)b * NHEADS_ + h) * NN_ + qglob] = lacc[0] + Ls[wq * 32 + l31];
    }
  }
  __syncthreads();  // all Od reads complete before Of overwrites the region
  // phase 3: wk==0 writes the bf16 partial-O transpose buffer
  if (wk == 0) {
    #pragma unroll
    for (int dgrp = 0; dgrp < 2; ++dgrp)
      #pragma unroll
      for (int rg = 0; rg < 16; ++rg) {
        int d = dgrp * 32 + (rg & 3) + 8 * (rg >> 2) + 4 * hi;
        Of[(wq * 32 + l31) * 68 + d] = f32_to_bf16u(oacc[dgrp][rg]);
      }
  }
  __syncthreads();
  // cooperative coalesced store of the partial: 128 q-rows x 128 B
  #pragma unroll
  for (int itr = 0; itr < 2; ++itr) {
    int idx = itr * 512 + tid;   // 0..1023
    int qq = idx >> 3;           // 0..127
    int ck = idx & 7;            // 16B chunk
    u16x8 v = *reinterpret_cast<const u16x8*>(&Of[qq * 68 + ck * 8]);
    *reinterpret_cast<u16x8*>(od + base_q + (size_t)(r * QB + qq) * DIM_ + ck * 8) = v;
  }
}

// ---------------- reduce: ob = (O0 + O1) / (l0 + l1) -----------------------
__global__ __launch_bounds__(256)
void reduce_o(const u16* __restrict__ O0, const u16* __restrict__ O1,
              const float* __restrict__ L0, const float* __restrict__ L1,
              u16* __restrict__ ob) {
  int gid = blockIdx.x * blockDim.x + threadIdx.x;   // over B*N*DIM/8
  int flat = gid * 8;
  int c  = flat & (DIM_ - 1);
  int bq = flat >> 10;            // DIM_=1024
  int h  = c >> 6;
  int b  = bq >> 11;              // NN_=2048
  int q  = bq & (NN_ - 1);
  size_t li = ((size_t)b * NHEADS_ + h) * NN_ + q;
  float inv = 1.f / (L0[li] + L1[li]);
  u16x8 a = reinterpret_cast<const u16x8*>(O0)[gid];
  u16x8 bb = reinterpret_cast<const u16x8*>(O1)[gid];
  u16x8 o;
  #pragma unroll
  for (int j = 0; j < 8; ++j)
    o[j] = f32_to_bf16u((bf16u_to_f32(a[j]) + bf16u_to_f32(bb[j])) * inv);
  reinterpret_cast<u16x8*>(ob)[gid] = o;
}

// ---------------- launch ----------------
extern "C" void kernel_launch(void* const* d_in, const int* in_sizes, int n_in,
                              void* d_out, int out_size, void* d_ws, size_t ws_size,
                              hipStream_t stream) {
  (void)in_sizes; (void)n_in; (void)out_size; (void)ws_size;
  const float* x1 = (const float*)d_in[0];
  const float* x2 = (const float*)d_in[1];
  const float* Wq = (const float*)d_in[2];
  const float* bq = (const float*)d_in[3];
  const float* Wk = (const float*)d_in[4];
  const float* bk = (const float*)d_in[5];
  const float* Wv = (const float*)d_in[6];
  const float* bv = (const float*)d_in[7];
  const float* Wo = (const float*)d_in[8];
  const float* bo = (const float*)d_in[9];
  float* out = (float*)d_out;

  char* ws = (char*)d_ws;
  u16* x1b = (u16*)(ws);                       // 8 MB (dead after qkv)
  u16* x2b = (u16*)(ws + (8u  << 20));         // 8 MB (dead after qkv)
  u16* Wqb = (u16*)(ws + (16u << 20));         // 2 MB (dead after qkv)
  u16* Wkb = (u16*)(ws + (18u << 20));
  u16* Wvb = (u16*)(ws + (20u << 20));
  u16* Wob = (u16*)(ws + (22u << 20));         // live until gemm_o
  u16* qb  = (u16*)(ws + (24u << 20));         // 8 MB each
  u16* kb  = (u16*)(ws + (32u << 20));
  u16* vb  = (u16*)(ws + (40u << 20));
  u16* ob  = (u16*)(ws + (48u << 20));         // total 56 MB
  // attn partials overlay the dead regions (stream-ordered: qkv completes first)
  u16*   O0 = x1b;                              // 8 MB bf16 partial (half 0)
  u16*   O1 = x2b;                              // 8 MB bf16 partial (half 1)
  float* L0 = (float*)Wqb;                      // 256 KB
  float* L1 = (float*)(ws + (16u << 20) + (512u << 10)); // 256 KB (within Wqb's 2MB)

  cast_all<<<dim3(512, 6), 256, 0, stream>>>(x1, x1b, x2, x2b, Wq, Wqb,
                                             Wk, Wkb, Wv, Wvb, Wo, Wob);

  const int Mrows = BB_ * NN_;  // 4096
  dim3 gqkv(Mrows / BM, DIM_ / BN, 3);  // (32, 8, 3)
  gemm_qkv<<<gqkv, 512, 0, stream>>>(x1b, x2b, Wqb, bq, qb, Wkb, bk, kb, Wvb, bv, vb);

  dim3 ga(NN_ / QB, NHEADS_, BB_ * 2);  // (16, 16, 4) = 1024 blocks (kv-split-2)
  attn_fwd<<<ga, 512, 0, stream>>>(qb, kb, vb, O0, O1, L0, L1);

  // reduce partials -> ob
  reduce_o<<<(BB_ * NN_ * DIM_ / 8) / 256, 256, 0, stream>>>(O0, O1, L0, L1, ob);

  dim3 gg(Mrows / BM, DIM_ / BN);  // (32, 8)
  gemm_o<<<gg, 512, 0, stream>>>(ob, Wob, bo, out);
}

// Round 16
// 117.062 us; speedup vs baseline: 1.1633x; 1.1633x over previous
//
#include <hip/hip_runtime.h>
#include <stdint.h>

typedef unsigned short u16;
typedef __attribute__((ext_vector_type(4))) float f32x4;
typedef __attribute__((ext_vector_type(16))) float f32x16;
typedef __attribute__((ext_vector_type(8))) __bf16 bf16x8;
typedef __attribute__((ext_vector_type(8))) unsigned short u16x8;
typedef __attribute__((ext_vector_type(4))) unsigned short u16x4;

#define DIM_    1024
#define NHEADS_ 16
#define HD_     64
#define BB_     2
#define NN_     2048
#define MM_     2048

// 0.125 * log2(e): folded into Q projection so softmax runs in base-2.
#define QSCALE 0.180336884f

__device__ inline u16 f32_to_bf16u(float f) {
  union { float f; uint32_t u; } x; x.f = f;
  uint32_t r = x.u + 0x7FFFu + ((x.u >> 16) & 1u);
  return (u16)(r >> 16);
}

__device__ inline void gload_lds16(const u16* g, u16* l) {
  u16* gnc = const_cast<u16*>(g);
  __builtin_amdgcn_global_load_lds(
      (__attribute__((address_space(1))) void*)gnc,
      (__attribute__((address_space(3))) void*)l, 16, 0, 0);
}

__device__ inline uint32_t cvt_pk_bf16(float lo, float hi) {
  uint32_t r;
  asm("v_cvt_pk_bf16_f32 %0, %1, %2" : "=v"(r) : "v"(lo), "v"(hi));
  return r;
}
__device__ inline void permlane32_swap(uint32_t& a, uint32_t& b) {
  asm("v_permlane32_swap_b32 %0, %1" : "+v"(a), "+v"(b));
}

// ---------------- fused cast fp32 -> bf16 (all 6 tensors, one launch) ------
__global__ void cast_all(const float* s0, u16* d0, const float* s1, u16* d1,
                         const float* s2, u16* d2, const float* s3, u16* d3,
                         const float* s4, u16* d4, const float* s5, u16* d5) {
  const float* s; u16* d; int n4;
  switch (blockIdx.y) {
    case 0: s = s0; d = d0; n4 = (BB_ * NN_ * DIM_) / 4; break;
    case 1: s = s1; d = d1; n4 = (BB_ * MM_ * DIM_) / 4; break;
    case 2: s = s2; d = d2; n4 = (DIM_ * DIM_) / 4; break;
    case 3: s = s3; d = d3; n4 = (DIM_ * DIM_) / 4; break;
    case 4: s = s4; d = d4; n4 = (DIM_ * DIM_) / 4; break;
    default: s = s5; d = d5; n4 = (DIM_ * DIM_) / 4; break;
  }
  int stride = gridDim.x * blockDim.x;
  for (int i = blockIdx.x * blockDim.x + threadIdx.x; i < n4; i += stride) {
    float4 f = reinterpret_cast<const float4*>(s)[i];
    u16x4 u;
    u.x = f32_to_bf16u(f.x);
    u.y = f32_to_bf16u(f.y);
    u.z = f32_to_bf16u(f.z);
    u.w = f32_to_bf16u(f.w);
    reinterpret_cast<u16x4*>(d)[i] = u;
  }
}

// ---------------- shared tile geometry ----------------
#define BM 128
#define BN 128
#define BK2 32

// ---------- BK=32 GEMM body: LDS 32 KB -> 3 blocks/CU. bf16 A and W.
// BK=32 swizzle: granule = (4*row + ch) % 8 -> chunk key (row>>1)&3.
// Applied BOTH sides: pre-swizzled gload source + swizzled frag reads.
template <bool BF16OUT>
__device__ __forceinline__
void gemm32_body(const u16* __restrict__ A, const u16* __restrict__ W,
                 const float* __restrict__ bias, void* __restrict__ Cout,
                 float scale, u16* As, u16* Bs) {
  const int K = DIM_;
  const int tid  = threadIdx.x;
  const int lane = tid & 63;
  const int wid  = tid >> 6;
  const int wr = wid >> 2, wc = wid & 3;
  const int fr = lane & 15, fq = lane >> 4;
  const int bm = blockIdx.x, bn = blockIdx.y;

  const int srow = tid >> 2;                        // 0..127
  const int sch  = tid & 3;                         // chunk 0..3
  const int scol = ((sch ^ ((srow >> 1) & 3)) * 8); // pre-swizzled src col (u16)
  const int rsw  = (fr >> 1) & 3;                   // read-side swizzle key

  f32x4 acc[4][2];
  #pragma unroll
  for (int m = 0; m < 4; ++m)
    #pragma unroll
    for (int n = 0; n < 2; ++n)
      acc[m][n] = f32x4{0.f, 0.f, 0.f, 0.f};

  const int NT = K / BK2;   // 32

  auto stage = [&](int buf, int t) {
    int k0 = t * BK2;
    gload_lds16(A + (size_t)(bm * BM + srow) * K + k0 + scol, &As[buf * BM * BK2 + tid * 8]);
    gload_lds16(W + (size_t)(bn * BN + srow) * K + k0 + scol, &Bs[buf * BN * BK2 + tid * 8]);
  };

  stage(0, 0);
  __syncthreads();
  int cur = 0;
  for (int t = 0; t < NT; ++t) {
    if (t + 1 < NT) stage(cur ^ 1, t + 1);
    bf16x8 af[4], bfr[2];
    #pragma unroll
    for (int m = 0; m < 4; ++m)
      af[m] = *reinterpret_cast<const bf16x8*>(
          &As[cur * BM * BK2 + (wr * 64 + m * 16 + fr) * BK2 + ((fq ^ rsw) * 8)]);
    #pragma unroll
    for (int n = 0; n < 2; ++n)
      bfr[n] = *reinterpret_cast<const bf16x8*>(
          &Bs[cur * BN * BK2 + (wc * 32 + n * 16 + fr) * BK2 + ((fq ^ rsw) * 8)]);
    __builtin_amdgcn_s_setprio(1);
    #pragma unroll
    for (int m = 0; m < 4; ++m)
      #pragma unroll
      for (int n = 0; n < 2; ++n)
        acc[m][n] = __builtin_amdgcn_mfma_f32_16x16x32_bf16(af[m], bfr[n], acc[m][n], 0, 0, 0);
    __builtin_amdgcn_s_setprio(0);
    __syncthreads();
    cur ^= 1;
  }

  #pragma unroll
  for (int n = 0; n < 2; ++n) {
    int col = bn * BN + wc * 32 + n * 16 + fr;
    float bv = bias[col];
    #pragma unroll
    for (int m = 0; m < 4; ++m) {
      #pragma unroll
      for (int i = 0; i < 4; ++i) {
        int row = bm * BM + wr * 64 + m * 16 + fq * 4 + i;
        float v = (acc[m][n][i] + bv) * scale;
        if (BF16OUT)
          ((u16*)Cout)[(size_t)row * DIM_ + col] = f32_to_bf16u(v);
        else
          ((float*)Cout)[(size_t)row * DIM_ + col] = v;
      }
    }
  }
}

// Fused Q/K/V projection (BK=32), grid.z selects the matmul.
__global__ __launch_bounds__(512)
void gemm_qkv(const u16* __restrict__ x1b, const u16* __restrict__ x2b,
              const u16* __restrict__ Wqb, const float* __restrict__ bq, u16* qb,
              const u16* __restrict__ Wkb, const float* __restrict__ bk, u16* kb,
              const u16* __restrict__ Wvb, const float* __restrict__ bv, u16* vb) {
  __shared__ __align__(16) u16 As[2 * BM * BK2];   // 16 KB
  __shared__ __align__(16) u16 Bs[2 * BN * BK2];   // 16 KB
  const u16* A; const u16* W; const float* bias; u16* C; float scale;
  switch (blockIdx.z) {
    case 0:  A = x1b; W = Wqb; bias = bq; C = qb; scale = QSCALE; break;
    case 1:  A = x2b; W = Wkb; bias = bk; C = kb; scale = 1.0f;   break;
    default: A = x2b; W = Wvb; bias = bv; C = vb; scale = 1.0f;   break;
  }
  gemm32_body<true>(A, W, bias, C, scale, As, Bs);
}

// O projection (fp32 out), BK=32 body (3 blocks/CU vs 2 at BK=64).
__global__ __launch_bounds__(512)
void gemm_o(const u16* __restrict__ A, const u16* __restrict__ W,
            const float* __restrict__ bias, float* __restrict__ C) {
  __shared__ __align__(16) u16 As[2 * BM * BK2];
  __shared__ __align__(16) u16 Bs[2 * BN * BK2];
  gemm32_body<false>(A, W, bias, C, 1.0f, As, Bs);
}

// ---------------- flash attention, 32x32 MFMA (R10/R14 proven version) -----
// 512 blocks (XCD-swizzled), 512 threads = 8 waves = 4 q-groups x 2 kv-halves.
// Swapped QK^T (mfma_32x32x16(K,Q) -> S^T[kv][q] in regs); P in-register via
// cvt_pk+permlane32_swap; no-max base-2 softmax; l via ones-A MFMA.
// 3-buffer LDS ring (48 KB), prefetch depth 2, 1 barrier/tile.
// Epilogue: padded transpose with barrier-separated phases.
#define QB 128
#define KVB 64

__global__ __launch_bounds__(512)
void attn_fwd(const u16* __restrict__ qg, const u16* __restrict__ kg,
              const u16* __restrict__ vg, u16* __restrict__ og) {
  __shared__ __align__(16) u16 KVs[6 * KVB * HD_];   // 3 K bufs + 3 VT bufs = 48 KB
  const int tid = threadIdx.x, lane = tid & 63, wid = tid >> 6;
  const int hi = lane >> 5;          // half-wave index
  const int l31 = lane & 31;
  const int wq = wid >> 1, wk = wid & 1;

  // XCD-aware swizzle (bijective: 512 = 8 xcd * 16 r * 4 gg)
  int lin = blockIdx.x + gridDim.x * (blockIdx.y + gridDim.y * blockIdx.z);
  int xcd = lin & 7, slot = lin >> 3;
  int r = slot & 15, gg2 = slot >> 4;
  int g = xcd + 8 * gg2;             // bh group 0..31
  int h = g & 15, b = g >> 4;

  const size_t base_q  = (size_t)b * NN_ * DIM_ + (size_t)h * HD_;
  const size_t base_kv = (size_t)b * MM_ * DIM_ + (size_t)h * HD_;
  const int lrow = lane >> 3;
  const int scol = (((lane & 7) ^ lrow) * 8);   // pre-swizzled K source col

  // Q fragments, B-layout [16 d][32 q]: lane holds Q[q=l31][step*16+hi*8+j]
  bf16x8 qf[4];
  const int qrow = r * QB + wq * 32 + l31;
  #pragma unroll
  for (int step = 0; step < 4; ++step)
    qf[step] = *reinterpret_cast<const bf16x8*>(
        qg + base_q + (size_t)qrow * DIM_ + step * 16 + hi * 8);

  // all-ones A fragment (layout-independent) for the l row-sum MFMA
  bf16x8 onesf;
  #pragma unroll
  for (int j = 0; j < 8; ++j) onesf[j] = (__bf16)1.0f;

  f32x16 oacc[2];
  #pragma unroll
  for (int dgrp = 0; dgrp < 2; ++dgrp)
    #pragma unroll
    for (int rg = 0; rg < 16; ++rg) oacc[dgrp][rg] = 0.f;
  f32x16 lacc;
  #pragma unroll
  for (int rg = 0; rg < 16; ++rg) lacc[rg] = 0.f;

  const int NT = MM_ / KVB;

  auto stageK = [&](int buf, int t) {
    int kv0 = t * KVB;
    int row = wid * 8 + lrow;   // 0..63
    gload_lds16(kg + base_kv + (size_t)(kv0 + row) * DIM_ + scol,
                &KVs[buf * 4096 + wid * 512]);
  };
  auto loadV = [&](int t, u16x8& vpre) {
    int kv0 = t * KVB;
    vpre = *reinterpret_cast<const u16x8*>(vg + base_kv + (size_t)(kv0 + lane) * DIM_ + wid * 8);
  };
  auto writeVT = [&](int buf, const u16x8& vpre) {
    #pragma unroll
    for (int j = 0; j < 8; ++j)
      KVs[(3 + buf) * 4096 + (wid * 8 + j) * KVB + (((lane >> 3) ^ j) * 8) + (lane & 7)] = vpre[j];
  };

  union PB { uint32_t w[4]; bf16x8 v; };

  auto compute = [&](int buf) {
    const u16* Kb = &KVs[buf * 4096];
    const u16* Vb = &KVs[(3 + buf) * 4096];
    // ---- QK^T swapped (32x32x16): S^T[kv=wk half][q] ----
    f32x16 s;
    #pragma unroll
    for (int rg = 0; rg < 16; ++rg) s[rg] = 0.f;
    __builtin_amdgcn_s_setprio(1);
    #pragma unroll
    for (int step = 0; step < 4; ++step) {
      bf16x8 kf = *reinterpret_cast<const bf16x8*>(
          (const char*)Kb + (wk * 32 + l31) * 128 + (((step * 2 + hi) ^ (lane & 7)) * 16));
      s = __builtin_amdgcn_mfma_f32_32x32x16_bf16(kf, qf[step], s, 0, 0, 0);
    }
    __builtin_amdgcn_s_setprio(0);

    // ---- no-max softmax: p = exp2(s) ----
    float p[16];
    #pragma unroll
    for (int rg = 0; rg < 16; ++rg) p[rg] = __builtin_amdgcn_exp2f(s[rg]);

    // ---- pack P^T into PV B-frags in-register (cvt_pk + permlane32_swap) --
    PB pb[2];
    #pragma unroll
    for (int u = 0; u < 2; ++u) {
      uint32_t x0 = cvt_pk_bf16(p[u * 8 + 0], p[u * 8 + 1]);
      uint32_t y0 = cvt_pk_bf16(p[u * 8 + 4], p[u * 8 + 5]);
      permlane32_swap(x0, y0);
      uint32_t x1 = cvt_pk_bf16(p[u * 8 + 2], p[u * 8 + 3]);
      uint32_t y1 = cvt_pk_bf16(p[u * 8 + 6], p[u * 8 + 7]);
      permlane32_swap(x1, y1);
      pb[u].w[0] = x0; pb[u].w[1] = x1; pb[u].w[2] = y0; pb[u].w[3] = y1;
    }

    // ---- PV (32x32x16): O^T[d][q] += V^T[d][kv] P^T[kv][q]; l = 1^T P ----
    __builtin_amdgcn_s_setprio(1);
    #pragma unroll
    for (int u = 0; u < 2; ++u)
      lacc = __builtin_amdgcn_mfma_f32_32x32x16_bf16(onesf, pb[u].v, lacc, 0, 0, 0);
    #pragma unroll
    for (int dgrp = 0; dgrp < 2; ++dgrp)
      #pragma unroll
      for (int u = 0; u < 2; ++u) {
        bf16x8 vf = *reinterpret_cast<const bf16x8*>(
            (const char*)Vb + (dgrp * 32 + l31) * 128 +
            (((wk * 4 + u * 2 + hi) ^ (lane & 7)) * 16));
        oacc[dgrp] = __builtin_amdgcn_mfma_f32_32x32x16_bf16(vf, pb[u].v, oacc[dgrp], 0, 0, 0);
      }
    __builtin_amdgcn_s_setprio(0);
  };

  // prologue: stage tiles 0,1 into bufs 0,1
  {
    u16x8 v0, v1;
    loadV(0, v0);
    loadV(1, v1);
    stageK(0, 0);
    stageK(1, 1);
    writeVT(0, v0);
    writeVT(1, v1);
    __syncthreads();
  }

  // main loop: 3-buffer ring, prefetch t+2 while computing t, 1 barrier/tile.
  int cur = 0, stg = 2;
  for (int t = 0; t < NT; ++t) {
    u16x8 vpre;
    bool pre = (t + 2 < NT);
    if (pre) {
      loadV(t + 2, vpre);
      stageK(stg, t + 2);
    }
    compute(cur);
    if (pre) writeVT(stg, vpre);
    __syncthreads();
    cur = (cur == 2) ? 0 : cur + 1;
    stg = (stg == 2) ? 0 : stg + 1;
  }

  // ---- epilogue: cross-wk O/l reduction, padded transpose, 3 fenced phases --
  float* Od = (float*)&KVs[0];             // [128][65] f32 = 33280 B
  float* Ls = (float*)&KVs[0] + 128 * 65;  // [128] f32 (disjoint)
  u16*  Of  = (u16*)&KVs[0];               // [128][68] u16 overlay of Od region

  // phase 1: wk==1 publishes its partial O and l
  if (wk == 1) {
    #pragma unroll
    for (int dgrp = 0; dgrp < 2; ++dgrp)
      #pragma unroll
      for (int rg = 0; rg < 16; ++rg) {
        int d = dgrp * 32 + (rg & 3) + 8 * (rg >> 2) + 4 * hi;
        Od[(wq * 32 + l31) * 65 + d] = oacc[dgrp][rg];
      }
    if (hi == 0) Ls[wq * 32 + l31] = lacc[0];
  }
  __syncthreads();
  // phase 2: wk==0 reduces into registers and scales (reads only)
  if (wk == 0) {
    float inv = 1.f / (lacc[0] + Ls[wq * 32 + l31]);
    #pragma unroll
    for (int dgrp = 0; dgrp < 2; ++dgrp)
      #pragma unroll
      for (int rg = 0; rg < 16; ++rg) {
        int d = dgrp * 32 + (rg & 3) + 8 * (rg >> 2) + 4 * hi;
        oacc[dgrp][rg] = (oacc[dgrp][rg] + Od[(wq * 32 + l31) * 65 + d]) * inv;
      }
  }
  __syncthreads();  // ALL Od reads complete before Of overwrites the region
  // phase 3: wk==0 writes the bf16 transpose buffer
  if (wk == 0) {
    #pragma unroll
    for (int dgrp = 0; dgrp < 2; ++dgrp)
      #pragma unroll
      for (int rg = 0; rg < 16; ++rg) {
        int d = dgrp * 32 + (rg & 3) + 8 * (rg >> 2) + 4 * hi;
        Of[(wq * 32 + l31) * 68 + d] = f32_to_bf16u(oacc[dgrp][rg]);
      }
  }
  __syncthreads();
  // cooperative coalesced store: 128 q-rows x 128 B
  #pragma unroll
  for (int itr = 0; itr < 2; ++itr) {
    int idx = itr * 512 + tid;   // 0..1023
    int qq = idx >> 3;           // 0..127
    int ck = idx & 7;            // 16B chunk
    u16x8 v = *reinterpret_cast<const u16x8*>(&Of[qq * 68 + ck * 8]);
    *reinterpret_cast<u16x8*>(og + base_q + (size_t)(r * QB + qq) * DIM_ + ck * 8) = v;
  }
}

// ---------------- launch ----------------
extern "C" void kernel_launch(void* const* d_in, const int* in_sizes, int n_in,
                              void* d_out, int out_size, void* d_ws, size_t ws_size,
                              hipStream_t stream) {
  (void)in_sizes; (void)n_in; (void)out_size; (void)ws_size;
  const float* x1 = (const float*)d_in[0];
  const float* x2 = (const float*)d_in[1];
  const float* Wq = (const float*)d_in[2];
  const float* bq = (const float*)d_in[3];
  const float* Wk = (const float*)d_in[4];
  const float* bk = (const float*)d_in[5];
  const float* Wv = (const float*)d_in[6];
  const float* bv = (const float*)d_in[7];
  const float* Wo = (const float*)d_in[8];
  const float* bo = (const float*)d_in[9];
  float* out = (float*)d_out;

  char* ws = (char*)d_ws;
  u16* x1b = (u16*)(ws);                       // 8 MB
  u16* x2b = (u16*)(ws + (8u  << 20));         // 8 MB
  u16* Wqb = (u16*)(ws + (16u << 20));         // 2 MB each
  u16* Wkb = (u16*)(ws + (18u << 20));
  u16* Wvb = (u16*)(ws + (20u << 20));
  u16* Wob = (u16*)(ws + (22u << 20));
  u16* qb  = (u16*)(ws + (24u << 20));         // 8 MB each
  u16* kb  = (u16*)(ws + (32u << 20));
  u16* vb  = (u16*)(ws + (40u << 20));
  u16* ob  = (u16*)(ws + (48u << 20));         // total 56 MB

  cast_all<<<dim3(512, 6), 256, 0, stream>>>(x1, x1b, x2, x2b, Wq, Wqb,
                                             Wk, Wkb, Wv, Wvb, Wo, Wob);

  const int Mrows = BB_ * NN_;  // 4096
  dim3 gqkv(Mrows / BM, DIM_ / BN, 3);  // (32, 8, 3)
  gemm_qkv<<<gqkv, 512, 0, stream>>>(x1b, x2b, Wqb, bq, qb, Wkb, bk, kb, Wvb, bv, vb);

  dim3 ga(NN_ / QB, NHEADS_, BB_);  // (16, 16, 2)
  attn_fwd<<<ga, 512, 0, stream>>>(qb, kb, vb, ob);

  dim3 gg(Mrows / BM, DIM_ / BN);  // (32, 8)
  gemm_o<<<gg, 512, 0, stream>>>(ob, Wob, bo, out);
}

// Round 17
// 115.342 us; speedup vs baseline: 1.1806x; 1.0149x over previous
//
#include <hip/hip_runtime.h>
#include <stdint.h>

typedef unsigned short u16;
typedef __attribute__((ext_vector_type(4))) float f32x4;
typedef __attribute__((ext_vector_type(16))) float f32x16;
typedef __attribute__((ext_vector_type(8))) __bf16 bf16x8;
typedef __attribute__((ext_vector_type(8))) unsigned short u16x8;
typedef __attribute__((ext_vector_type(4))) unsigned short u16x4;

#define DIM_    1024
#define NHEADS_ 16
#define HD_     64
#define BB_     2
#define NN_     2048
#define MM_     2048

// 0.125 * log2(e): folded into Q projection so softmax runs in base-2.
#define QSCALE 0.180336884f

__device__ inline u16 f32_to_bf16u(float f) {
  union { float f; uint32_t u; } x; x.f = f;
  uint32_t r = x.u + 0x7FFFu + ((x.u >> 16) & 1u);
  return (u16)(r >> 16);
}

__device__ inline void gload_lds16(const u16* g, u16* l) {
  u16* gnc = const_cast<u16*>(g);
  __builtin_amdgcn_global_load_lds(
      (__attribute__((address_space(1))) void*)gnc,
      (__attribute__((address_space(3))) void*)l, 16, 0, 0);
}

__device__ inline uint32_t cvt_pk_bf16(float lo, float hi) {
  uint32_t r;
  asm("v_cvt_pk_bf16_f32 %0, %1, %2" : "=v"(r) : "v"(lo), "v"(hi));
  return r;
}
__device__ inline void permlane32_swap(uint32_t& a, uint32_t& b) {
  asm("v_permlane32_swap_b32 %0, %1" : "+v"(a), "+v"(b));
}

// ---------------- fused cast fp32 -> bf16 (all 6 tensors, one launch) ------
__global__ void cast_all(const float* s0, u16* d0, const float* s1, u16* d1,
                         const float* s2, u16* d2, const float* s3, u16* d3,
                         const float* s4, u16* d4, const float* s5, u16* d5) {
  const float* s; u16* d; int n4;
  switch (blockIdx.y) {
    case 0: s = s0; d = d0; n4 = (BB_ * NN_ * DIM_) / 4; break;
    case 1: s = s1; d = d1; n4 = (BB_ * MM_ * DIM_) / 4; break;
    case 2: s = s2; d = d2; n4 = (DIM_ * DIM_) / 4; break;
    case 3: s = s3; d = d3; n4 = (DIM_ * DIM_) / 4; break;
    case 4: s = s4; d = d4; n4 = (DIM_ * DIM_) / 4; break;
    default: s = s5; d = d5; n4 = (DIM_ * DIM_) / 4; break;
  }
  int stride = gridDim.x * blockDim.x;
  for (int i = blockIdx.x * blockDim.x + threadIdx.x; i < n4; i += stride) {
    float4 f = reinterpret_cast<const float4*>(s)[i];
    u16x4 u;
    u.x = f32_to_bf16u(f.x);
    u.y = f32_to_bf16u(f.y);
    u.z = f32_to_bf16u(f.z);
    u.w = f32_to_bf16u(f.w);
    reinterpret_cast<u16x4*>(d)[i] = u;
  }
}

// ---------------- GEMM core (BK=64) : used by gemm_o -----------------------
#define BM 128
#define BN 128
#define BK 64

template <bool BF16OUT>
__device__ __forceinline__
void gemm_body(const u16* __restrict__ A, const u16* __restrict__ Bm,
               const float* __restrict__ bias, void* __restrict__ Cout,
               int M, int N, int K, float scale,
               u16* As /*2*BM*BK*/, u16* Bs /*2*BN*BK*/) {
  const int tid  = threadIdx.x;
  const int lane = tid & 63;
  const int wid  = tid >> 6;
  const int wr = wid >> 2, wc = wid & 3;          // 2 x 4 wave grid
  const int fr = lane & 15, fq = lane >> 4;
  const int bm = blockIdx.x, bn = blockIdx.y;
  const int lrow = lane >> 3;                     // 0..7
  const int scol = (((lane & 7) ^ lrow) * 8);     // pre-swizzled source col

  f32x4 acc[4][2];
  #pragma unroll
  for (int m = 0; m < 4; ++m)
    #pragma unroll
    for (int n = 0; n < 2; ++n)
      acc[m][n] = f32x4{0.f, 0.f, 0.f, 0.f};

  const int NT = K / BK;

  auto stage = [&](int buf, int t) {
    int k0 = t * BK;
    #pragma unroll
    for (int c = 0; c < 2; ++c) {
      int ch  = wid * 2 + c;           // 0..15
      int row = ch * 8 + lrow;         // 0..127
      gload_lds16(A  + (size_t)(bm * BM + row) * K + k0 + scol, &As[buf * BM * BK + ch * 512]);
      gload_lds16(Bm + (size_t)(bn * BN + row) * K + k0 + scol, &Bs[buf * BN * BK + ch * 512]);
    }
  };

  stage(0, 0);
  __syncthreads();
  int cur = 0;
  for (int t = 0; t < NT; ++t) {
    if (t + 1 < NT) stage(cur ^ 1, t + 1);
    #pragma unroll
    for (int ks = 0; ks < 2; ++ks) {
      bf16x8 af[4], bfr[2];
      #pragma unroll
      for (int m = 0; m < 4; ++m)
        af[m] = *reinterpret_cast<const bf16x8*>(
            &As[cur * BM * BK + (wr * 64 + m * 16 + fr) * BK + (((ks * 4 + fq) ^ (fr & 7)) * 8)]);
      #pragma unroll
      for (int n = 0; n < 2; ++n)
        bfr[n] = *reinterpret_cast<const bf16x8*>(
            &Bs[cur * BN * BK + (wc * 32 + n * 16 + fr) * BK + (((ks * 4 + fq) ^ (fr & 7)) * 8)]);
      __builtin_amdgcn_s_setprio(1);
      #pragma unroll
      for (int m = 0; m < 4; ++m)
        #pragma unroll
        for (int n = 0; n < 2; ++n)
          acc[m][n] = __builtin_amdgcn_mfma_f32_16x16x32_bf16(af[m], bfr[n], acc[m][n], 0, 0, 0);
      __builtin_amdgcn_s_setprio(0);
    }
    __syncthreads();
    cur ^= 1;
  }

  #pragma unroll
  for (int n = 0; n < 2; ++n) {
    int col = bn * BN + wc * 32 + n * 16 + fr;
    float bv = bias[col];
    #pragma unroll
    for (int m = 0; m < 4; ++m) {
      #pragma unroll
      for (int i = 0; i < 4; ++i) {
        int row = bm * BM + wr * 64 + m * 16 + fq * 4 + i;
        float v = (acc[m][n][i] + bv) * scale;
        if (BF16OUT)
          ((u16*)Cout)[(size_t)row * N + col] = f32_to_bf16u(v);
        else
          ((float*)Cout)[(size_t)row * N + col] = v;
      }
    }
  }
}

// ---------- QKV GEMM, BK=32 (R14 proven): LDS 32 KB, 3 blocks/CU at 768 ----
#define BK2 32

__global__ __launch_bounds__(512)
void gemm_qkv(const u16* __restrict__ x1b, const u16* __restrict__ x2b,
              const u16* __restrict__ Wqb, const float* __restrict__ bq, u16* qb,
              const u16* __restrict__ Wkb, const float* __restrict__ bk, u16* kb,
              const u16* __restrict__ Wvb, const float* __restrict__ bv, u16* vb) {
  __shared__ __align__(16) u16 As[2 * BM * BK2];   // 16 KB
  __shared__ __align__(16) u16 Bs[2 * BN * BK2];   // 16 KB
  const u16* A; const u16* W; const float* bias; u16* C; float scale;
  switch (blockIdx.z) {
    case 0:  A = x1b; W = Wqb; bias = bq; C = qb; scale = QSCALE; break;
    case 1:  A = x2b; W = Wkb; bias = bk; C = kb; scale = 1.0f;   break;
    default: A = x2b; W = Wvb; bias = bv; C = vb; scale = 1.0f;   break;
  }
  const int K = DIM_;
  const int tid  = threadIdx.x;
  const int lane = tid & 63;
  const int wid  = tid >> 6;
  const int wr = wid >> 2, wc = wid & 3;
  const int fr = lane & 15, fq = lane >> 4;
  const int bm = blockIdx.x, bn = blockIdx.y;

  const int srow = tid >> 2;                        // 0..127
  const int sch  = tid & 3;                         // chunk 0..3
  const int scol = ((sch ^ ((srow >> 1) & 3)) * 8); // pre-swizzled src col (u16)
  const int rsw  = (fr >> 1) & 3;                   // read-side swizzle key

  f32x4 acc[4][2];
  #pragma unroll
  for (int m = 0; m < 4; ++m)
    #pragma unroll
    for (int n = 0; n < 2; ++n)
      acc[m][n] = f32x4{0.f, 0.f, 0.f, 0.f};

  const int NT = K / BK2;   // 32

  auto stage = [&](int buf, int t) {
    int k0 = t * BK2;
    gload_lds16(A + (size_t)(bm * BM + srow) * K + k0 + scol, &As[buf * BM * BK2 + tid * 8]);
    gload_lds16(W + (size_t)(bn * BN + srow) * K + k0 + scol, &Bs[buf * BN * BK2 + tid * 8]);
  };

  stage(0, 0);
  __syncthreads();
  int cur = 0;
  for (int t = 0; t < NT; ++t) {
    if (t + 1 < NT) stage(cur ^ 1, t + 1);
    bf16x8 af[4], bfr[2];
    #pragma unroll
    for (int m = 0; m < 4; ++m)
      af[m] = *reinterpret_cast<const bf16x8*>(
          &As[cur * BM * BK2 + (wr * 64 + m * 16 + fr) * BK2 + ((fq ^ rsw) * 8)]);
    #pragma unroll
    for (int n = 0; n < 2; ++n)
      bfr[n] = *reinterpret_cast<const bf16x8*>(
          &Bs[cur * BN * BK2 + (wc * 32 + n * 16 + fr) * BK2 + ((fq ^ rsw) * 8)]);
    __builtin_amdgcn_s_setprio(1);
    #pragma unroll
    for (int m = 0; m < 4; ++m)
      #pragma unroll
      for (int n = 0; n < 2; ++n)
        acc[m][n] = __builtin_amdgcn_mfma_f32_16x16x32_bf16(af[m], bfr[n], acc[m][n], 0, 0, 0);
    __builtin_amdgcn_s_setprio(0);
    __syncthreads();
    cur ^= 1;
  }

  #pragma unroll
  for (int n = 0; n < 2; ++n) {
    int col = bn * BN + wc * 32 + n * 16 + fr;
    float bv = bias[col];
    #pragma unroll
    for (int m = 0; m < 4; ++m) {
      #pragma unroll
      for (int i = 0; i < 4; ++i) {
        int row = bm * BM + wr * 64 + m * 16 + fq * 4 + i;
        float v = (acc[m][n][i] + bv) * scale;
        C[(size_t)row * DIM_ + col] = f32_to_bf16u(v);
      }
    }
  }
}

// O projection (fp32 out), bf16 A (attn output) + bf16 W, BK=64 core (R14).
__global__ __launch_bounds__(512)
void gemm_o(const u16* __restrict__ A, const u16* __restrict__ W,
            const float* __restrict__ bias, float* __restrict__ C) {
  __shared__ __align__(16) u16 As[2 * BM * BK];
  __shared__ __align__(16) u16 Bs[2 * BN * BK];
  gemm_body<false>(A, W, bias, C, BB_ * NN_, DIM_, DIM_, 1.0f, As, Bs);
}

// ---------------- flash attention, 32x32 MFMA (R10/R14 proven version) -----
// 512 blocks (XCD-swizzled), 512 threads = 8 waves = 4 q-groups x 2 kv-halves.
// Swapped QK^T (mfma_32x32x16(K,Q) -> S^T[kv][q] in regs); P in-register via
// cvt_pk+permlane32_swap; no-max base-2 softmax; l via ones-A MFMA.
// 3-buffer LDS ring (48 KB), prefetch depth 2, 1 barrier/tile.
// Epilogue: padded transpose with barrier-separated phases.
#define QB 128
#define KVB 64

__global__ __launch_bounds__(512)
void attn_fwd(const u16* __restrict__ qg, const u16* __restrict__ kg,
              const u16* __restrict__ vg, u16* __restrict__ og) {
  __shared__ __align__(16) u16 KVs[6 * KVB * HD_];   // 3 K bufs + 3 VT bufs = 48 KB
  const int tid = threadIdx.x, lane = tid & 63, wid = tid >> 6;
  const int hi = lane >> 5;          // half-wave index
  const int l31 = lane & 31;
  const int wq = wid >> 1, wk = wid & 1;

  // XCD-aware swizzle (bijective: 512 = 8 xcd * 16 r * 4 gg)
  int lin = blockIdx.x + gridDim.x * (blockIdx.y + gridDim.y * blockIdx.z);
  int xcd = lin & 7, slot = lin >> 3;
  int r = slot & 15, gg2 = slot >> 4;
  int g = xcd + 8 * gg2;             // bh group 0..31
  int h = g & 15, b = g >> 4;

  const size_t base_q  = (size_t)b * NN_ * DIM_ + (size_t)h * HD_;
  const size_t base_kv = (size_t)b * MM_ * DIM_ + (size_t)h * HD_;
  const int lrow = lane >> 3;
  const int scol = (((lane & 7) ^ lrow) * 8);   // pre-swizzled K source col

  // Q fragments, B-layout [16 d][32 q]: lane holds Q[q=l31][step*16+hi*8+j]
  bf16x8 qf[4];
  const int qrow = r * QB + wq * 32 + l31;
  #pragma unroll
  for (int step = 0; step < 4; ++step)
    qf[step] = *reinterpret_cast<const bf16x8*>(
        qg + base_q + (size_t)qrow * DIM_ + step * 16 + hi * 8);

  // all-ones A fragment (layout-independent) for the l row-sum MFMA
  bf16x8 onesf;
  #pragma unroll
  for (int j = 0; j < 8; ++j) onesf[j] = (__bf16)1.0f;

  f32x16 oacc[2];
  #pragma unroll
  for (int dgrp = 0; dgrp < 2; ++dgrp)
    #pragma unroll
    for (int rg = 0; rg < 16; ++rg) oacc[dgrp][rg] = 0.f;
  f32x16 lacc;
  #pragma unroll
  for (int rg = 0; rg < 16; ++rg) lacc[rg] = 0.f;

  const int NT = MM_ / KVB;

  auto stageK = [&](int buf, int t) {
    int kv0 = t * KVB;
    int row = wid * 8 + lrow;   // 0..63
    gload_lds16(kg + base_kv + (size_t)(kv0 + row) * DIM_ + scol,
                &KVs[buf * 4096 + wid * 512]);
  };
  auto loadV = [&](int t, u16x8& vpre) {
    int kv0 = t * KVB;
    vpre = *reinterpret_cast<const u16x8*>(vg + base_kv + (size_t)(kv0 + lane) * DIM_ + wid * 8);
  };
  auto writeVT = [&](int buf, const u16x8& vpre) {
    #pragma unroll
    for (int j = 0; j < 8; ++j)
      KVs[(3 + buf) * 4096 + (wid * 8 + j) * KVB + (((lane >> 3) ^ j) * 8) + (lane & 7)] = vpre[j];
  };

  union PB { uint32_t w[4]; bf16x8 v; };

  auto compute = [&](int buf) {
    const u16* Kb = &KVs[buf * 4096];
    const u16* Vb = &KVs[(3 + buf) * 4096];
    // ---- QK^T swapped (32x32x16): S^T[kv=wk half][q] ----
    f32x16 s;
    #pragma unroll
    for (int rg = 0; rg < 16; ++rg) s[rg] = 0.f;
    __builtin_amdgcn_s_setprio(1);
    #pragma unroll
    for (int step = 0; step < 4; ++step) {
      bf16x8 kf = *reinterpret_cast<const bf16x8*>(
          (const char*)Kb + (wk * 32 + l31) * 128 + (((step * 2 + hi) ^ (lane & 7)) * 16));
      s = __builtin_amdgcn_mfma_f32_32x32x16_bf16(kf, qf[step], s, 0, 0, 0);
    }
    __builtin_amdgcn_s_setprio(0);

    // ---- no-max softmax: p = exp2(s) ----
    float p[16];
    #pragma unroll
    for (int rg = 0; rg < 16; ++rg) p[rg] = __builtin_amdgcn_exp2f(s[rg]);

    // ---- pack P^T into PV B-frags in-register (cvt_pk + permlane32_swap) --
    PB pb[2];
    #pragma unroll
    for (int u = 0; u < 2; ++u) {
      uint32_t x0 = cvt_pk_bf16(p[u * 8 + 0], p[u * 8 + 1]);
      uint32_t y0 = cvt_pk_bf16(p[u * 8 + 4], p[u * 8 + 5]);
      permlane32_swap(x0, y0);
      uint32_t x1 = cvt_pk_bf16(p[u * 8 + 2], p[u * 8 + 3]);
      uint32_t y1 = cvt_pk_bf16(p[u * 8 + 6], p[u * 8 + 7]);
      permlane32_swap(x1, y1);
      pb[u].w[0] = x0; pb[u].w[1] = x1; pb[u].w[2] = y0; pb[u].w[3] = y1;
    }

    // ---- PV (32x32x16): O^T[d][q] += V^T[d][kv] P^T[kv][q]; l = 1^T P ----
    __builtin_amdgcn_s_setprio(1);
    #pragma unroll
    for (int u = 0; u < 2; ++u)
      lacc = __builtin_amdgcn_mfma_f32_32x32x16_bf16(onesf, pb[u].v, lacc, 0, 0, 0);
    #pragma unroll
    for (int dgrp = 0; dgrp < 2; ++dgrp)
      #pragma unroll
      for (int u = 0; u < 2; ++u) {
        bf16x8 vf = *reinterpret_cast<const bf16x8*>(
            (const char*)Vb + (dgrp * 32 + l31) * 128 +
            (((wk * 4 + u * 2 + hi) ^ (lane & 7)) * 16));
        oacc[dgrp] = __builtin_amdgcn_mfma_f32_32x32x16_bf16(vf, pb[u].v, oacc[dgrp], 0, 0, 0);
      }
    __builtin_amdgcn_s_setprio(0);
  };

  // prologue: stage tiles 0,1 into bufs 0,1
  {
    u16x8 v0, v1;
    loadV(0, v0);
    loadV(1, v1);
    stageK(0, 0);
    stageK(1, 1);
    writeVT(0, v0);
    writeVT(1, v1);
    __syncthreads();
  }

  // main loop: 3-buffer ring, prefetch t+2 while computing t, 1 barrier/tile.
  int cur = 0, stg = 2;
  for (int t = 0; t < NT; ++t) {
    u16x8 vpre;
    bool pre = (t + 2 < NT);
    if (pre) {
      loadV(t + 2, vpre);
      stageK(stg, t + 2);
    }
    compute(cur);
    if (pre) writeVT(stg, vpre);
    __syncthreads();
    cur = (cur == 2) ? 0 : cur + 1;
    stg = (stg == 2) ? 0 : stg + 1;
  }

  // ---- epilogue: cross-wk O/l reduction, padded transpose, 3 fenced phases --
  float* Od = (float*)&KVs[0];             // [128][65] f32 = 33280 B
  float* Ls = (float*)&KVs[0] + 128 * 65;  // [128] f32 (disjoint)
  u16*  Of  = (u16*)&KVs[0];               // [128][68] u16 overlay of Od region

  // phase 1: wk==1 publishes its partial O and l
  if (wk == 1) {
    #pragma unroll
    for (int dgrp = 0; dgrp < 2; ++dgrp)
      #pragma unroll
      for (int rg = 0; rg < 16; ++rg) {
        int d = dgrp * 32 + (rg & 3) + 8 * (rg >> 2) + 4 * hi;
        Od[(wq * 32 + l31) * 65 + d] = oacc[dgrp][rg];
      }
    if (hi == 0) Ls[wq * 32 + l31] = lacc[0];
  }
  __syncthreads();
  // phase 2: wk==0 reduces into registers and scales (reads only)
  if (wk == 0) {
    float inv = 1.f / (lacc[0] + Ls[wq * 32 + l31]);
    #pragma unroll
    for (int dgrp = 0; dgrp < 2; ++dgrp)
      #pragma unroll
      for (int rg = 0; rg < 16; ++rg) {
        int d = dgrp * 32 + (rg & 3) + 8 * (rg >> 2) + 4 * hi;
        oacc[dgrp][rg] = (oacc[dgrp][rg] + Od[(wq * 32 + l31) * 65 + d]) * inv;
      }
  }
  __syncthreads();  // ALL Od reads complete before Of overwrites the region
  // phase 3: wk==0 writes the bf16 transpose buffer
  if (wk == 0) {
    #pragma unroll
    for (int dgrp = 0; dgrp < 2; ++dgrp)
      #pragma unroll
      for (int rg = 0; rg < 16; ++rg) {
        int d = dgrp * 32 + (rg & 3) + 8 * (rg >> 2) + 4 * hi;
        Of[(wq * 32 + l31) * 68 + d] = f32_to_bf16u(oacc[dgrp][rg]);
      }
  }
  __syncthreads();
  // cooperative coalesced store: 128 q-rows x 128 B
  #pragma unroll
  for (int itr = 0; itr < 2; ++itr) {
    int idx = itr * 512 + tid;   // 0..1023
    int qq = idx >> 3;           // 0..127
    int ck = idx & 7;            // 16B chunk
    u16x8 v = *reinterpret_cast<const u16x8*>(&Of[qq * 68 + ck * 8]);
    *reinterpret_cast<u16x8*>(og + base_q + (size_t)(r * QB + qq) * DIM_ + ck * 8) = v;
  }
}

// ---------------- launch ----------------
extern "C" void kernel_launch(void* const* d_in, const int* in_sizes, int n_in,
                              void* d_out, int out_size, void* d_ws, size_t ws_size,
                              hipStream_t stream) {
  (void)in_sizes; (void)n_in; (void)out_size; (void)ws_size;
  const float* x1 = (const float*)d_in[0];
  const float* x2 = (const float*)d_in[1];
  const float* Wq = (const float*)d_in[2];
  const float* bq = (const float*)d_in[3];
  const float* Wk = (const float*)d_in[4];
  const float* bk = (const float*)d_in[5];
  const float* Wv = (const float*)d_in[6];
  const float* bv = (const float*)d_in[7];
  const float* Wo = (const float*)d_in[8];
  const float* bo = (const float*)d_in[9];
  float* out = (float*)d_out;

  char* ws = (char*)d_ws;
  u16* x1b = (u16*)(ws);                       // 8 MB
  u16* x2b = (u16*)(ws + (8u  << 20));         // 8 MB
  u16* Wqb = (u16*)(ws + (16u << 20));         // 2 MB each
  u16* Wkb = (u16*)(ws + (18u << 20));
  u16* Wvb = (u16*)(ws + (20u << 20));
  u16* Wob = (u16*)(ws + (22u << 20));
  u16* qb  = (u16*)(ws + (24u << 20));         // 8 MB each
  u16* kb  = (u16*)(ws + (32u << 20));
  u16* vb  = (u16*)(ws + (40u << 20));
  u16* ob  = (u16*)(ws + (48u << 20));         // total 56 MB

  cast_all<<<dim3(512, 6), 256, 0, stream>>>(x1, x1b, x2, x2b, Wq, Wqb,
                                             Wk, Wkb, Wv, Wvb, Wo, Wob);

  const int Mrows = BB_ * NN_;  // 4096
  dim3 gqkv(Mrows / BM, DIM_ / BN, 3);  // (32, 8, 3)
  gemm_qkv<<<gqkv, 512, 0, stream>>>(x1b, x2b, Wqb, bq, qb, Wkb, bk, kb, Wvb, bv, vb);

  dim3 ga(NN_ / QB, NHEADS_, BB_);  // (16, 16, 2)
  attn_fwd<<<ga, 512, 0, stream>>>(qb, kb, vb, ob);

  dim3 gg(Mrows / BM, DIM_ / BN);  // (32, 8)
  gemm_o<<<gg, 512, 0, stream>>>(ob, Wob, bo, out);
}

// Round 18
// 112.455 us; speedup vs baseline: 1.2109x; 1.0257x over previous
//
#include <hip/hip_runtime.h>
#include <stdint.h>

typedef unsigned short u16;
typedef __attribute__((ext_vector_type(4))) float f32x4;
typedef __attribute__((ext_vector_type(16))) float f32x16;
typedef __attribute__((ext_vector_type(8))) __bf16 bf16x8;
typedef __attribute__((ext_vector_type(8))) unsigned short u16x8;
typedef __attribute__((ext_vector_type(4))) unsigned short u16x4;

#define DIM_    1024
#define NHEADS_ 16
#define HD_     64
#define BB_     2
#define NN_     2048
#define MM_     2048

// 0.125 * log2(e): folded into Q projection so softmax runs in base-2.
#define QSCALE 0.180336884f

__device__ inline u16 f32_to_bf16u(float f) {
  union { float f; uint32_t u; } x; x.f = f;
  uint32_t r = x.u + 0x7FFFu + ((x.u >> 16) & 1u);
  return (u16)(r >> 16);
}

__device__ inline void gload_lds16(const u16* g, u16* l) {
  u16* gnc = const_cast<u16*>(g);
  __builtin_amdgcn_global_load_lds(
      (__attribute__((address_space(1))) void*)gnc,
      (__attribute__((address_space(3))) void*)l, 16, 0, 0);
}

__device__ inline uint32_t cvt_pk_bf16(float lo, float hi) {
  uint32_t r;
  asm("v_cvt_pk_bf16_f32 %0, %1, %2" : "=v"(r) : "v"(lo), "v"(hi));
  return r;
}
__device__ inline void permlane32_swap(uint32_t& a, uint32_t& b) {
  asm("v_permlane32_swap_b32 %0, %1" : "+v"(a), "+v"(b));
}

// ---------------- fused cast fp32 -> bf16 (all 6 tensors, one launch) ------
__global__ void cast_all(const float* s0, u16* d0, const float* s1, u16* d1,
                         const float* s2, u16* d2, const float* s3, u16* d3,
                         const float* s4, u16* d4, const float* s5, u16* d5) {
  const float* s; u16* d; int n4;
  switch (blockIdx.y) {
    case 0: s = s0; d = d0; n4 = (BB_ * NN_ * DIM_) / 4; break;
    case 1: s = s1; d = d1; n4 = (BB_ * MM_ * DIM_) / 4; break;
    case 2: s = s2; d = d2; n4 = (DIM_ * DIM_) / 4; break;
    case 3: s = s3; d = d3; n4 = (DIM_ * DIM_) / 4; break;
    case 4: s = s4; d = d4; n4 = (DIM_ * DIM_) / 4; break;
    default: s = s5; d = d5; n4 = (DIM_ * DIM_) / 4; break;
  }
  int stride = gridDim.x * blockDim.x;
  for (int i = blockIdx.x * blockDim.x + threadIdx.x; i < n4; i += stride) {
    float4 f = reinterpret_cast<const float4*>(s)[i];
    u16x4 u;
    u.x = f32_to_bf16u(f.x);
    u.y = f32_to_bf16u(f.y);
    u.z = f32_to_bf16u(f.z);
    u.w = f32_to_bf16u(f.w);
    reinterpret_cast<u16x4*>(d)[i] = u;
  }
}

// ---------------- GEMM core (BK=64) : used by gemm_o -----------------------
#define BM 128
#define BN 128
#define BK 64

template <bool BF16OUT>
__device__ __forceinline__
void gemm_body(const u16* __restrict__ A, const u16* __restrict__ Bm,
               const float* __restrict__ bias, void* __restrict__ Cout,
               int M, int N, int K, float scale,
               u16* As /*2*BM*BK*/, u16* Bs /*2*BN*BK*/) {
  const int tid  = threadIdx.x;
  const int lane = tid & 63;
  const int wid  = tid >> 6;
  const int wr = wid >> 2, wc = wid & 3;          // 2 x 4 wave grid
  const int fr = lane & 15, fq = lane >> 4;
  const int bm = blockIdx.x, bn = blockIdx.y;
  const int lrow = lane >> 3;                     // 0..7
  const int scol = (((lane & 7) ^ lrow) * 8);     // pre-swizzled source col

  f32x4 acc[4][2];
  #pragma unroll
  for (int m = 0; m < 4; ++m)
    #pragma unroll
    for (int n = 0; n < 2; ++n)
      acc[m][n] = f32x4{0.f, 0.f, 0.f, 0.f};

  const int NT = K / BK;

  auto stage = [&](int buf, int t) {
    int k0 = t * BK;
    #pragma unroll
    for (int c = 0; c < 2; ++c) {
      int ch  = wid * 2 + c;           // 0..15
      int row = ch * 8 + lrow;         // 0..127
      gload_lds16(A  + (size_t)(bm * BM + row) * K + k0 + scol, &As[buf * BM * BK + ch * 512]);
      gload_lds16(Bm + (size_t)(bn * BN + row) * K + k0 + scol, &Bs[buf * BN * BK + ch * 512]);
    }
  };

  stage(0, 0);
  __syncthreads();
  int cur = 0;
  for (int t = 0; t < NT; ++t) {
    if (t + 1 < NT) stage(cur ^ 1, t + 1);
    #pragma unroll
    for (int ks = 0; ks < 2; ++ks) {
      bf16x8 af[4], bfr[2];
      #pragma unroll
      for (int m = 0; m < 4; ++m)
        af[m] = *reinterpret_cast<const bf16x8*>(
            &As[cur * BM * BK + (wr * 64 + m * 16 + fr) * BK + (((ks * 4 + fq) ^ (fr & 7)) * 8)]);
      #pragma unroll
      for (int n = 0; n < 2; ++n)
        bfr[n] = *reinterpret_cast<const bf16x8*>(
            &Bs[cur * BN * BK + (wc * 32 + n * 16 + fr) * BK + (((ks * 4 + fq) ^ (fr & 7)) * 8)]);
      __builtin_amdgcn_s_setprio(1);
      #pragma unroll
      for (int m = 0; m < 4; ++m)
        #pragma unroll
        for (int n = 0; n < 2; ++n)
          acc[m][n] = __builtin_amdgcn_mfma_f32_16x16x32_bf16(af[m], bfr[n], acc[m][n], 0, 0, 0);
      __builtin_amdgcn_s_setprio(0);
    }
    __syncthreads();
    cur ^= 1;
  }

  #pragma unroll
  for (int n = 0; n < 2; ++n) {
    int col = bn * BN + wc * 32 + n * 16 + fr;
    float bv = bias[col];
    #pragma unroll
    for (int m = 0; m < 4; ++m) {
      #pragma unroll
      for (int i = 0; i < 4; ++i) {
        int row = bm * BM + wr * 64 + m * 16 + fq * 4 + i;
        float v = (acc[m][n][i] + bv) * scale;
        if (BF16OUT)
          ((u16*)Cout)[(size_t)row * N + col] = f32_to_bf16u(v);
        else
          ((float*)Cout)[(size_t)row * N + col] = v;
      }
    }
  }
}

// ---------- QKV GEMM, BK=32 (R14 proven): LDS 32 KB, 3 blocks/CU at 768 ----
// z==2 (V projection) writes its output TRANSPOSED as vbT[b*1024+dglobal][m]
// via an LDS transpose (padded stride 132), so attn can DMA-stage V^T tiles
// exactly like K tiles (no per-lane scatter in the attn hot loop).
#define BK2 32

__global__ __launch_bounds__(512)
void gemm_qkv(const u16* __restrict__ x1b, const u16* __restrict__ x2b,
              const u16* __restrict__ Wqb, const float* __restrict__ bq, u16* qb,
              const u16* __restrict__ Wkb, const float* __restrict__ bk, u16* kb,
              const u16* __restrict__ Wvb, const float* __restrict__ bv, u16* vbT) {
  __shared__ __align__(16) u16 SMEM[16896];   // As(8192) + Bs(8192); TL[128][132] overlay
  u16* As = SMEM;
  u16* Bs = SMEM + 2 * BM * BK2;
  const u16* A; const u16* W; const float* bias; float scale;
  switch (blockIdx.z) {
    case 0:  A = x1b; W = Wqb; bias = bq; scale = QSCALE; break;
    case 1:  A = x2b; W = Wkb; bias = bk; scale = 1.0f;   break;
    default: A = x2b; W = Wvb; bias = bv; scale = 1.0f;   break;
  }
  const int K = DIM_;
  const int tid  = threadIdx.x;
  const int lane = tid & 63;
  const int wid  = tid >> 6;
  const int wr = wid >> 2, wc = wid & 3;
  const int fr = lane & 15, fq = lane >> 4;
  const int bm = blockIdx.x, bn = blockIdx.y;

  const int srow = tid >> 2;                        // 0..127
  const int sch  = tid & 3;                         // chunk 0..3
  const int scol = ((sch ^ ((srow >> 1) & 3)) * 8); // pre-swizzled src col (u16)
  const int rsw  = (fr >> 1) & 3;                   // read-side swizzle key

  f32x4 acc[4][2];
  #pragma unroll
  for (int m = 0; m < 4; ++m)
    #pragma unroll
    for (int n = 0; n < 2; ++n)
      acc[m][n] = f32x4{0.f, 0.f, 0.f, 0.f};

  const int NT = K / BK2;   // 32

  auto stage = [&](int buf, int t) {
    int k0 = t * BK2;
    gload_lds16(A + (size_t)(bm * BM + srow) * K + k0 + scol, &As[buf * BM * BK2 + tid * 8]);
    gload_lds16(W + (size_t)(bn * BN + srow) * K + k0 + scol, &Bs[buf * BN * BK2 + tid * 8]);
  };

  stage(0, 0);
  __syncthreads();
  int cur = 0;
  for (int t = 0; t < NT; ++t) {
    if (t + 1 < NT) stage(cur ^ 1, t + 1);
    bf16x8 af[4], bfr[2];
    #pragma unroll
    for (int m = 0; m < 4; ++m)
      af[m] = *reinterpret_cast<const bf16x8*>(
          &As[cur * BM * BK2 + (wr * 64 + m * 16 + fr) * BK2 + ((fq ^ rsw) * 8)]);
    #pragma unroll
    for (int n = 0; n < 2; ++n)
      bfr[n] = *reinterpret_cast<const bf16x8*>(
          &Bs[cur * BN * BK2 + (wc * 32 + n * 16 + fr) * BK2 + ((fq ^ rsw) * 8)]);
    __builtin_amdgcn_s_setprio(1);
    #pragma unroll
    for (int m = 0; m < 4; ++m)
      #pragma unroll
      for (int n = 0; n < 2; ++n)
        acc[m][n] = __builtin_amdgcn_mfma_f32_16x16x32_bf16(af[m], bfr[n], acc[m][n], 0, 0, 0);
    __builtin_amdgcn_s_setprio(0);
    __syncthreads();
    cur ^= 1;
  }
  // (loop's final barrier fenced all LDS reads; SMEM reusable below)

  if (blockIdx.z != 2) {
    u16* C = (blockIdx.z == 0) ? qb : kb;
    #pragma unroll
    for (int n = 0; n < 2; ++n) {
      int col = bn * BN + wc * 32 + n * 16 + fr;
      float bv = bias[col];
      #pragma unroll
      for (int m = 0; m < 4; ++m) {
        #pragma unroll
        for (int i = 0; i < 4; ++i) {
          int row = bm * BM + wr * 64 + m * 16 + fq * 4 + i;
          float v = (acc[m][n][i] + bv) * scale;
          C[(size_t)row * DIM_ + col] = f32_to_bf16u(v);
        }
      }
    }
  } else {
    // V: transpose tile through LDS (TL[col][row], stride 132 -> ~2-way),
    // then store coalesced rows of V^T.
    #pragma unroll
    for (int n = 0; n < 2; ++n) {
      int col = wc * 32 + n * 16 + fr;            // local d
      float bv = bias[bn * BN + col];
      #pragma unroll
      for (int m = 0; m < 4; ++m) {
        #pragma unroll
        for (int i = 0; i < 4; ++i) {
          int row = wr * 64 + m * 16 + fq * 4 + i; // local m
          SMEM[col * 132 + row] = f32_to_bf16u(acc[m][n][i] + bv);
        }
      }
    }
    __syncthreads();
    const int bb = bm >> 4;                 // batch of this m-tile (2048/128=16)
    const int mmb = (bm & 15) * 128;        // m offset within batch
    #pragma unroll
    for (int itr = 0; itr < 4; ++itr) {
      int idx = itr * 512 + tid;            // 0..2047
      int dl = idx >> 4;                    // local d row 0..127
      int ck = idx & 15;                    // 8-u16 chunk within 128 m
      u16x8 v = *reinterpret_cast<const u16x8*>(&SMEM[dl * 132 + ck * 8]);
      *reinterpret_cast<u16x8*>(
          vbT + ((size_t)bb * 1024 + bn * BN + dl) * (size_t)MM_ + mmb + ck * 8) = v;
    }
  }
}

// O projection (fp32 out), bf16 A (attn output) + bf16 W, BK=64 core (R14).
__global__ __launch_bounds__(512)
void gemm_o(const u16* __restrict__ A, const u16* __restrict__ W,
            const float* __restrict__ bias, float* __restrict__ C) {
  __shared__ __align__(16) u16 As[2 * BM * BK];
  __shared__ __align__(16) u16 Bs[2 * BN * BK];
  gemm_body<false>(A, W, bias, C, BB_ * NN_, DIM_, DIM_, 1.0f, As, Bs);
}

// ---------------- flash attention, 32x32 MFMA, DMA-staged K and V^T --------
// 512 blocks (XCD-swizzled), 512 threads = 8 waves = 4 q-groups x 2 kv-halves.
// V arrives pre-transposed (vbT[d][m]) so BOTH tiles stage via global_load_lds
// with the pre-swizzled-source pattern -- no per-lane LDS scatter, no reg
// staging. Compute loop identical to the R10/R14 proven version.
#define QB 128
#define KVB 64

__global__ __launch_bounds__(512)
void attn_fwd(const u16* __restrict__ qg, const u16* __restrict__ kg,
              const u16* __restrict__ vtg, u16* __restrict__ og) {
  __shared__ __align__(16) u16 KVs[6 * KVB * HD_];   // 3 K bufs + 3 VT bufs = 48 KB
  const int tid = threadIdx.x, lane = tid & 63, wid = tid >> 6;
  const int hi = lane >> 5;          // half-wave index
  const int l31 = lane & 31;
  const int wq = wid >> 1, wk = wid & 1;

  // XCD-aware swizzle (bijective: 512 = 8 xcd * 16 r * 4 gg)
  int lin = blockIdx.x + gridDim.x * (blockIdx.y + gridDim.y * blockIdx.z);
  int xcd = lin & 7, slot = lin >> 3;
  int r = slot & 15, gg2 = slot >> 4;
  int g = xcd + 8 * gg2;             // bh group 0..31
  int h = g & 15, b = g >> 4;

  const size_t base_q  = (size_t)b * NN_ * DIM_ + (size_t)h * HD_;
  const size_t base_kv = (size_t)b * MM_ * DIM_ + (size_t)h * HD_;
  const size_t base_vt = ((size_t)b * 1024 + (size_t)h * HD_) * (size_t)MM_;
  const int lrow = lane >> 3;
  const int scol = (((lane & 7) ^ lrow) * 8);   // pre-swizzled K source col

  // Q fragments, B-layout [16 d][32 q]: lane holds Q[q=l31][step*16+hi*8+j]
  bf16x8 qf[4];
  const int qrow = r * QB + wq * 32 + l31;
  #pragma unroll
  for (int step = 0; step < 4; ++step)
    qf[step] = *reinterpret_cast<const bf16x8*>(
        qg + base_q + (size_t)qrow * DIM_ + step * 16 + hi * 8);

  // all-ones A fragment (layout-independent) for the l row-sum MFMA
  bf16x8 onesf;
  #pragma unroll
  for (int j = 0; j < 8; ++j) onesf[j] = (__bf16)1.0f;

  f32x16 oacc[2];
  #pragma unroll
  for (int dgrp = 0; dgrp < 2; ++dgrp)
    #pragma unroll
    for (int rg = 0; rg < 16; ++rg) oacc[dgrp][rg] = 0.f;
  f32x16 lacc;
  #pragma unroll
  for (int rg = 0; rg < 16; ++rg) lacc[rg] = 0.f;

  const int NT = MM_ / KVB;

  auto stageK = [&](int buf, int t) {
    int kv0 = t * KVB;
    int row = wid * 8 + lrow;   // kv row 0..63
    gload_lds16(kg + base_kv + (size_t)(kv0 + row) * DIM_ + scol,
                &KVs[buf * 4096 + wid * 512]);
  };
  // V^T tile: row = d (0..63, stride MM_ in global), cols = kv chunk.
  // LDS chunk ck of row d holds global kv chunk ck^(d&7) -- same key the
  // vf reads use (lane&7 == d&7 there).
  auto stageVT = [&](int buf, int t) {
    int kv0 = t * KVB;
    int row = wid * 8 + lrow;                  // d row 0..63
    int scol2 = (((lane & 7) ^ (row & 7)) * 8);
    gload_lds16(vtg + base_vt + (size_t)row * MM_ + kv0 + scol2,
                &KVs[(3 + buf) * 4096 + wid * 512]);
  };

  union PB { uint32_t w[4]; bf16x8 v; };

  auto compute = [&](int buf) {
    const u16* Kb = &KVs[buf * 4096];
    const u16* Vb = &KVs[(3 + buf) * 4096];
    // ---- QK^T swapped (32x32x16): S^T[kv=wk half][q] ----
    f32x16 s;
    #pragma unroll
    for (int rg = 0; rg < 16; ++rg) s[rg] = 0.f;
    __builtin_amdgcn_s_setprio(1);
    #pragma unroll
    for (int step = 0; step < 4; ++step) {
      bf16x8 kf = *reinterpret_cast<const bf16x8*>(
          (const char*)Kb + (wk * 32 + l31) * 128 + (((step * 2 + hi) ^ (lane & 7)) * 16));
      s = __builtin_amdgcn_mfma_f32_32x32x16_bf16(kf, qf[step], s, 0, 0, 0);
    }
    __builtin_amdgcn_s_setprio(0);

    // ---- no-max softmax: p = exp2(s) ----
    float p[16];
    #pragma unroll
    for (int rg = 0; rg < 16; ++rg) p[rg] = __builtin_amdgcn_exp2f(s[rg]);

    // ---- pack P^T into PV B-frags in-register (cvt_pk + permlane32_swap) --
    PB pb[2];
    #pragma unroll
    for (int u = 0; u < 2; ++u) {
      uint32_t x0 = cvt_pk_bf16(p[u * 8 + 0], p[u * 8 + 1]);
      uint32_t y0 = cvt_pk_bf16(p[u * 8 + 4], p[u * 8 + 5]);
      permlane32_swap(x0, y0);
      uint32_t x1 = cvt_pk_bf16(p[u * 8 + 2], p[u * 8 + 3]);
      uint32_t y1 = cvt_pk_bf16(p[u * 8 + 6], p[u * 8 + 7]);
      permlane32_swap(x1, y1);
      pb[u].w[0] = x0; pb[u].w[1] = x1; pb[u].w[2] = y0; pb[u].w[3] = y1;
    }

    // ---- PV (32x32x16): O^T[d][q] += V^T[d][kv] P^T[kv][q]; l = 1^T P ----
    __builtin_amdgcn_s_setprio(1);
    #pragma unroll
    for (int u = 0; u < 2; ++u)
      lacc = __builtin_amdgcn_mfma_f32_32x32x16_bf16(onesf, pb[u].v, lacc, 0, 0, 0);
    #pragma unroll
    for (int dgrp = 0; dgrp < 2; ++dgrp)
      #pragma unroll
      for (int u = 0; u < 2; ++u) {
        bf16x8 vf = *reinterpret_cast<const bf16x8*>(
            (const char*)Vb + (dgrp * 32 + l31) * 128 +
            (((wk * 4 + u * 2 + hi) ^ (lane & 7)) * 16));
        oacc[dgrp] = __builtin_amdgcn_mfma_f32_32x32x16_bf16(vf, pb[u].v, oacc[dgrp], 0, 0, 0);
      }
    __builtin_amdgcn_s_setprio(0);
  };

  // prologue: stage tiles 0,1 into bufs 0,1 (pure DMA)
  stageK(0, 0); stageVT(0, 0);
  stageK(1, 1); stageVT(1, 1);
  __syncthreads();

  // main loop: 3-buffer ring, prefetch t+2 while computing t, 1 barrier/tile.
  int cur = 0, stg = 2;
  for (int t = 0; t < NT; ++t) {
    if (t + 2 < NT) {
      stageK(stg, t + 2);
      stageVT(stg, t + 2);
    }
    compute(cur);
    __syncthreads();
    cur = (cur == 2) ? 0 : cur + 1;
    stg = (stg == 2) ? 0 : stg + 1;
  }

  // ---- epilogue: cross-wk O/l reduction, padded transpose, 3 fenced phases --
  float* Od = (float*)&KVs[0];             // [128][65] f32 = 33280 B
  float* Ls = (float*)&KVs[0] + 128 * 65;  // [128] f32 (disjoint)
  u16*  Of  = (u16*)&KVs[0];               // [128][68] u16 overlay of Od region

  // phase 1: wk==1 publishes its partial O and l
  if (wk == 1) {
    #pragma unroll
    for (int dgrp = 0; dgrp < 2; ++dgrp)
      #pragma unroll
      for (int rg = 0; rg < 16; ++rg) {
        int d = dgrp * 32 + (rg & 3) + 8 * (rg >> 2) + 4 * hi;
        Od[(wq * 32 + l31) * 65 + d] = oacc[dgrp][rg];
      }
    if (hi == 0) Ls[wq * 32 + l31] = lacc[0];
  }
  __syncthreads();
  // phase 2: wk==0 reduces into registers and scales (reads only)
  if (wk == 0) {
    float inv = 1.f / (lacc[0] + Ls[wq * 32 + l31]);
    #pragma unroll
    for (int dgrp = 0; dgrp < 2; ++dgrp)
      #pragma unroll
      for (int rg = 0; rg < 16; ++rg) {
        int d = dgrp * 32 + (rg & 3) + 8 * (rg >> 2) + 4 * hi;
        oacc[dgrp][rg] = (oacc[dgrp][rg] + Od[(wq * 32 + l31) * 65 + d]) * inv;
      }
  }
  __syncthreads();  // ALL Od reads complete before Of overwrites the region
  // phase 3: wk==0 writes the bf16 transpose buffer
  if (wk == 0) {
    #pragma unroll
    for (int dgrp = 0; dgrp < 2; ++dgrp)
      #pragma unroll
      for (int rg = 0; rg < 16; ++rg) {
        int d = dgrp * 32 + (rg & 3) + 8 * (rg >> 2) + 4 * hi;
        Of[(wq * 32 + l31) * 68 + d] = f32_to_bf16u(oacc[dgrp][rg]);
      }
  }
  __syncthreads();
  // cooperative coalesced store: 128 q-rows x 128 B
  #pragma unroll
  for (int itr = 0; itr < 2; ++itr) {
    int idx = itr * 512 + tid;   // 0..1023
    int qq = idx >> 3;           // 0..127
    int ck = idx & 7;            // 16B chunk
    u16x8 v = *reinterpret_cast<const u16x8*>(&Of[qq * 68 + ck * 8]);
    *reinterpret_cast<u16x8*>(og + base_q + (size_t)(r * QB + qq) * DIM_ + ck * 8) = v;
  }
}

// ---------------- launch ----------------
extern "C" void kernel_launch(void* const* d_in, const int* in_sizes, int n_in,
                              void* d_out, int out_size, void* d_ws, size_t ws_size,
                              hipStream_t stream) {
  (void)in_sizes; (void)n_in; (void)out_size; (void)ws_size;
  const float* x1 = (const float*)d_in[0];
  const float* x2 = (const float*)d_in[1];
  const float* Wq = (const float*)d_in[2];
  const float* bq = (const float*)d_in[3];
  const float* Wk = (const float*)d_in[4];
  const float* bk = (const float*)d_in[5];
  const float* Wv = (const float*)d_in[6];
  const float* bv = (const float*)d_in[7];
  const float* Wo = (const float*)d_in[8];
  const float* bo = (const float*)d_in[9];
  float* out = (float*)d_out;

  char* ws = (char*)d_ws;
  u16* x1b = (u16*)(ws);                       // 8 MB
  u16* x2b = (u16*)(ws + (8u  << 20));         // 8 MB
  u16* Wqb = (u16*)(ws + (16u << 20));         // 2 MB each
  u16* Wkb = (u16*)(ws + (18u << 20));
  u16* Wvb = (u16*)(ws + (20u << 20));
  u16* Wob = (u16*)(ws + (22u << 20));
  u16* qb  = (u16*)(ws + (24u << 20));         // 8 MB each
  u16* kb  = (u16*)(ws + (32u << 20));
  u16* vbT = (u16*)(ws + (40u << 20));         // V^T [b*1024+dglobal][m]
  u16* ob  = (u16*)(ws + (48u << 20));         // total 56 MB

  cast_all<<<dim3(512, 6), 256, 0, stream>>>(x1, x1b, x2, x2b, Wq, Wqb,
                                             Wk, Wkb, Wv, Wvb, Wo, Wob);

  const int Mrows = BB_ * NN_;  // 4096
  dim3 gqkv(Mrows / BM, DIM_ / BN, 3);  // (32, 8, 3)
  gemm_qkv<<<gqkv, 512, 0, stream>>>(x1b, x2b, Wqb, bq, qb, Wkb, bk, kb, Wvb, bv, vbT);

  dim3 ga(NN_ / QB, NHEADS_, BB_);  // (16, 16, 2)
  attn_fwd<<<ga, 512, 0, stream>>>(qb, kb, vbT, ob);

  dim3 gg(Mrows / BM, DIM_ / BN);  // (32, 8)
  gemm_o<<<gg, 512, 0, stream>>>(ob, Wob, bo, out);
}